// Round 6
// baseline (189.960 us; speedup 1.0000x reference)
//
#include <hip/hip_runtime.h>

#define DD 256
#define NH 8
#define HPT 2    // heads per thread
#define NHG 4    // head-groups (threads per row)

constexpr float LN_EPS = 1e-5f;
constexpr float SCALE  = 0.0625f;         // 1/sqrt(256)
// Scaled-Schraudolph: xs holds x*KS (KS = ln2/2^23) so 1/|d_hat| IS the exp
// bit-argument; NR product fuses with the bias add in one fma.
constexpr float KS     = 8.2629579e-8f;   // ln2 / 2^23
constexpr float A_EXP  = 12102203.0f;     // 2^23 * log2(e) = 1/KS (sW rescale)
constexpr float B_EXP  = 1064986816.0f;   // 2^23 * (127 - 0.0436775)
#define RCP_MAGIC 0x7EF311C3u

// f = |y|*w + Bh; v_cvt_u32_f32 saturates neg/NaN -> 0 = exp underflow.
__device__ __forceinline__ float wexp_ys(float yabs, float w, float Bh) {
    float f = fmaf(yabs, w, Bh);
    unsigned u;
    asm("v_cvt_u32_f32 %0, %1" : "=v"(u) : "v"(f));
    return __uint_as_float(u);
}

// Reduce two values across a 1024-thread block (16 waves). All threads get it.
__device__ __forceinline__ float2 block_reduce2(float a, float b, float* sc, int tid) {
    #pragma unroll
    for (int off = 32; off; off >>= 1) {
        a += __shfl_down(a, off, 64);
        b += __shfl_down(b, off, 64);
    }
    __syncthreads();                      // protect sc from previous use
    if ((tid & 63) == 0) { int w = tid >> 6; sc[w] = a; sc[16 + w] = b; }
    __syncthreads();
    const float4* s4 = reinterpret_cast<const float4*>(sc);
    float4 a0 = s4[0], a1 = s4[1], a2 = s4[2], a3 = s4[3];
    float4 b0 = s4[4], b1 = s4[5], b2 = s4[6], b3 = s4[7];
    float ra = ((a0.x+a0.y)+(a0.z+a0.w)) + ((a1.x+a1.y)+(a1.z+a1.w))
             + ((a2.x+a2.y)+(a2.z+a2.w)) + ((a3.x+a3.y)+(a3.z+a3.w));
    float rb = ((b0.x+b0.y)+(b0.z+b0.w)) + ((b1.x+b1.y)+(b1.z+b1.w))
             + ((b2.x+b2.y)+(b2.z+b2.w)) + ((b3.x+b3.y)+(b3.z+b3.w));
    return make_float2(ra, rb);
}

template<int LAST>
__global__ __launch_bounds__(1024, 8) void flann_layer(
    const float* __restrict__ x_in,     // [B, DD]
    const float* __restrict__ alphas,   // [NH, 3] this layer
    const float* __restrict__ betas,    // [NH, 3]
    const float* __restrict__ g1, const float* __restrict__ b1,   // fla LN
    const float* __restrict__ W,  const float* __restrict__ wb,   // [DD,DD], [DD]
    const float* __restrict__ g2, const float* __restrict__ b2,   // lin LN
    const float* __restrict__ outW, const float* __restrict__ outB,
    float* __restrict__ out)            // [B,DD] or [B] if LAST
{
    __shared__ __align__(16) float xs[DD];          // x * KS
    __shared__ __align__(16) float xln[DD];
    __shared__ float comb[NHG][DD];                 // acc partials, then GEMM
    __shared__ float sc[32];

    const int tid  = threadIdx.x;
    const int i    = tid & (DD - 1);    // feature row this thread owns
    const int hg   = tid >> 8;          // head-group 0..3 (heads 2hg, 2hg+1)
    const int bidx = blockIdx.x;

    float xv = x_in[bidx * DD + i];
    if (hg == 0) xs[i] = xv * KS;
    __syncthreads();

    const float4* xs4 = reinterpret_cast<const float4*>(xs);

    // ---- params for my 2 heads (per-thread; whole softmax is thread-local) --
    float aqv[HPT], cv[HPT], dmn[HPT], Bv[HPT];
    #pragma unroll
    for (int hh = 0; hh < HPT; ++hh) {
        const int h = hg * HPT + hh;
        const float aq = alphas[h*3+0], ak = alphas[h*3+1];
        const float bq = betas [h*3+0], bk = betas [h*3+1];
        aqv[hh] = aq;
        cv[hh]  = (bq - fmaf(ak, xv, bk)) * KS;   // scaled c
        dmn[hh] = 1e38f;
    }

    // ---- pass 1: dmin per head over ALL j ----
    #pragma unroll 4
    for (int j4 = 0; j4 < DD/4; ++j4) {
        float4 xj = xs4[j4];                      // broadcast ds_read_b128
        #pragma unroll
        for (int hh = 0; hh < HPT; ++hh) {
            float d0 = fmaf(aqv[hh], xj.x, cv[hh]);
            float d1 = fmaf(aqv[hh], xj.y, cv[hh]);
            float d2 = fmaf(aqv[hh], xj.z, cv[hh]);
            float d3 = fmaf(aqv[hh], xj.w, cv[hh]);
            dmn[hh] = fminf(dmn[hh], fminf(fabsf(d0), fabsf(d1)));  // v_min3
            dmn[hh] = fminf(dmn[hh], fminf(fabsf(d2), fabsf(d3)));
        }
    }
    // Bh = B_EXP - m via the SAME seed+NR chain as pass 2 (bit-identical for
    // the argmin element -> top weight = 2^-sigma; exact-rcp m would flush
    // all weights to 0 at large m -> 0/0).
    #pragma unroll
    for (int hh = 0; hh < HPT; ++hh) {
        float dm = dmn[hh];
        float y  = __uint_as_float(RCP_MAGIC - __float_as_uint(dm));
        float w  = fmaf(-dm, fabsf(y), 2.0f);
        Bv[hh]   = B_EXP - fabsf(y) * w;
    }

    // ---- pass 2: e = bits(cvt(|y|*w + Bh)) over ALL j ----
    float sE[HPT], sW[HPT];
    #pragma unroll
    for (int hh = 0; hh < HPT; ++hh) { sE[hh] = 0.f; sW[hh] = 0.f; }

    #pragma unroll 4
    for (int j4 = 0; j4 < DD/4; ++j4) {
        float4 xj = xs4[j4];
        #pragma unroll
        for (int hh = 0; hh < HPT; ++hh) {
            const float aq = aqv[hh], c = cv[hh], Bh = Bv[hh];
            float dh0 = fmaf(aq, xj.x, c);
            float dh1 = fmaf(aq, xj.y, c);
            float dh2 = fmaf(aq, xj.z, c);
            float dh3 = fmaf(aq, xj.w, c);
            float y0 = __uint_as_float(RCP_MAGIC - __float_as_uint(dh0));
            float y1 = __uint_as_float(RCP_MAGIC - __float_as_uint(dh1));
            float y2 = __uint_as_float(RCP_MAGIC - __float_as_uint(dh2));
            float y3 = __uint_as_float(RCP_MAGIC - __float_as_uint(dh3));
            float w0 = fmaf(-fabsf(dh0), fabsf(y0), 2.0f);
            float w1 = fmaf(-fabsf(dh1), fabsf(y1), 2.0f);
            float w2 = fmaf(-fabsf(dh2), fabsf(y2), 2.0f);
            float w3 = fmaf(-fabsf(dh3), fabsf(y3), 2.0f);
            float e0 = wexp_ys(fabsf(y0), w0, Bh);
            float e1 = wexp_ys(fabsf(y1), w1, Bh);
            float e2 = wexp_ys(fabsf(y2), w2, Bh);
            float e3 = wexp_ys(fabsf(y3), w3, Bh);
            sE[hh] += e0; sW[hh] = fmaf(e0, xj.x, sW[hh]);
            sE[hh] += e1; sW[hh] = fmaf(e1, xj.y, sW[hh]);
            sE[hh] += e2; sW[hh] = fmaf(e2, xj.z, sW[hh]);
            sE[hh] += e3; sW[hh] = fmaf(e3, xj.w, sW[hh]);
        }
    }

    // per-thread partial of acc (additive over heads)
    float accp = 0.f;
    #pragma unroll
    for (int hh = 0; hh < HPT; ++hh) {
        const int h = hg * HPT + hh;
        const float av = alphas[h*3+2], bv = betas[h*3+2];
        float sWt = sW[hh] * A_EXP;               // undo KS scale
        accp += fmaf(av, sWt, bv * sE[hh]) * __builtin_amdgcn_rcpf(sE[hh]);
    }
    comb[hg][i] = accp;
    __syncthreads();

    // ---- combine head-groups, residual + ReLU (hg 0 only) ----
    float xr = 0.f;
    if (hg == 0) {
        float acc = (comb[0][i] + comb[1][i]) + (comb[2][i] + comb[3][i]);
        xr = fmaxf(fmaf(SCALE, acc, xv), 0.f);
    }

    // ---------------- LayerNorm 1 (hg!=0 contributes zeros) -----------------
    float2 r = block_reduce2(xr, xr * xr, sc, tid);
    float mu  = r.x * (1.f / DD);
    float var = r.y * (1.f / DD) - mu * mu;
    if (hg == 0) {
        float xn = (xr - mu) * __builtin_amdgcn_rsqf(var + LN_EPS);
        xln[i] = fmaf(xn, g1[i], b1[i]);
    }
    __syncthreads();

    // ---------------- Linear: d-range split 4 ways across hg ----------------
    const float4* xl4 = reinterpret_cast<const float4*>(xln);
    float ga0 = (hg == 0) ? wb[i] : 0.f, ga1 = 0.f, ga2 = 0.f, ga3 = 0.f;
    #pragma unroll 8
    for (int d4 = 0; d4 < DD/16; ++d4) {
        int g4 = hg * (DD/16) + d4;
        float4 xd = xl4[g4];
        int dr = 4 * g4;
        ga0 = fmaf(xd.x, W[(dr + 0) * DD + i], ga0);   // coalesced in i
        ga1 = fmaf(xd.y, W[(dr + 1) * DD + i], ga1);
        ga2 = fmaf(xd.z, W[(dr + 2) * DD + i], ga2);
        ga3 = fmaf(xd.w, W[(dr + 3) * DD + i], ga3);
    }
    comb[hg][i] = (ga0 + ga1) + (ga2 + ga3);
    __syncthreads();

    float gv = 0.f;
    if (hg == 0)
        gv = fmaxf((comb[0][i] + comb[1][i]) + (comb[2][i] + comb[3][i]), 0.f);

    // ---------------- LayerNorm 2 ----------------
    r = block_reduce2(gv, gv * gv, sc, tid);
    mu  = r.x * (1.f / DD);
    var = r.y * (1.f / DD) - mu * mu;
    float xo = 0.f;
    if (hg == 0)
        xo = fmaf((gv - mu) * __builtin_amdgcn_rsqf(var + LN_EPS), g2[i], b2[i]);

    if (!LAST) {
        if (hg == 0) out[bidx * DD + i] = xo;
    } else {
        float pr = (hg == 0) ? xo * outW[i] : 0.f;
        float2 p = block_reduce2(pr, 0.f, sc, tid);
        if (tid == 0) out[bidx] = p.x + outB[0];
    }
}

extern "C" void kernel_launch(void* const* d_in, const int* in_sizes, int n_in,
                              void* d_out, int out_size, void* d_ws, size_t ws_size,
                              hipStream_t stream) {
    const float* x      = (const float*)d_in[0];
    const float* alphas = (const float*)d_in[1];   // [L, NH, 3]
    const float* betas  = (const float*)d_in[2];   // [L, NH, 3]
    const float* flag   = (const float*)d_in[3];   // [L, DD]
    const float* flab   = (const float*)d_in[4];
    const float* linW   = (const float*)d_in[5];   // [L, DD, DD]
    const float* linb   = (const float*)d_in[6];   // [L, DD]
    const float* ling   = (const float*)d_in[7];
    const float* linb2  = (const float*)d_in[8];
    const float* outW   = (const float*)d_in[9];   // [DD]
    const float* outB   = (const float*)d_in[10];  // [1]

    const int B = in_sizes[0] / DD;
    float* ws   = (float*)d_ws;        // [B, DD] intermediate
    float* outp = (float*)d_out;       // [B]

    dim3 grid(B), block(1024);
    // layer 0: x -> ws
    flann_layer<0><<<grid, block, 0, stream>>>(
        x, alphas, betas, flag, flab, linW, linb, ling, linb2,
        nullptr, nullptr, ws);
    // layer 1 (+ fused final projection): ws -> out
    flann_layer<1><<<grid, block, 0, stream>>>(
        ws, alphas + NH*3, betas + NH*3, flag + DD, flab + DD,
        linW + DD*DD, linb + DD, ling + DD, linb2 + DD,
        outW, outB, outp);
}